// Round 1
// baseline (400.679 us; speedup 1.0000x reference)
//
#include <hip/hip_runtime.h>
#include <hip/hip_fp16.h>

// ---------------------------------------------------------------------------
// GCN (3 layers) + global mean pool + linear, fp32 in/out, MI355X.
// t'[i] = dinv[i] * h[i] W^T; h_next[i] = relu(dinv[i]*(t'[i]+sum t'[j]) + b)
// R3-R5: scattered 4B global stores/atomics = ~32B HBM sector each. Dense only.
// R9: fp16 t (128B row = 1 L2 line), absmax 1.2e-4.
// R11: LDS float-atomic scatter = never.
// R13/R18 (counter-verified): fusing agg with mm fails at ANY granularity
//   that cuts agg's wave count. agg must keep one node per wave (50000 waves).
// R16/R17: cooperative persistent kernel dead (not capturable; 840us anyway).
// R14: ~13us/launch of gap; launches are the #1 cost after kernel work.
// R19: sortfill_mm fusion worked (matched granularity). 9 launches, 308us.
// R20 (this round): fuse mm INTO agg at matched granularity. After the
//   shfl_xor(16,32) reduce every lane holds the full h row (chunk lane&15,
//   replicated x4), so the per-node matvec t_out[i][lane] = dinv*h.W[lane]
//   runs in-wave: v_readlane h-chunk broadcast + FMA vs reg-resident W row
//   (loaded in two 8-chunk halves behind sched_barrier to cap VGPR peak).
//   h1/h2 never hit HBM. agg3 fuses pool+linear via per-node z=h3.Wl^T
//   (chunk-aligned Wl frags + xor-reduce) and 16 atomicAdds into out
//   (init'd to bl). 9 -> 6 launches, -~70MB HBM/iter.
// ---------------------------------------------------------------------------

#define CAPB 3072
#define BINTILE 4096

__device__ __forceinline__ float rl_f(float v, int l) {
    return __int_as_float(__builtin_amdgcn_readlane(__float_as_int(v), l));
}

// fctr zero + per-graph inverse counts (binary search on sorted batch) +
// out seeded with bl (aggfinal accumulates atomically on top).
__global__ __launch_bounds__(256) void init_kernel(int* __restrict__ fctr,
                                                   const int* __restrict__ batch,
                                                   const float* __restrict__ bl,
                                                   float* __restrict__ invc,
                                                   float* __restrict__ out,
                                                   int n, int nb) {
    int t = blockIdx.x * blockDim.x + threadIdx.x;
    if (t < 512) fctr[t] = 0;
    if (t < nb) {
        int l = 0, r = n;
        while (l < r) { int m = (l + r) >> 1; if (batch[m] < t) l = m + 1; else r = m; }
        int lo = l;
        r = n;
        while (l < r) { int m = (l + r) >> 1; if (batch[m] < t + 1) l = m + 1; else r = m; }
        invc[t] = 1.0f / fmaxf((float)(l - lo), 1.0f);
#pragma unroll
        for (int o = 0; o < 16; ++o) out[t * 16 + o] = bl[o];
    }
}

// Bucket edges into 512 fine dst-ranges (fixed capacity CAPB, base=g*CAPB).
__global__ __launch_bounds__(256) void bin512_kernel(const int* __restrict__ src,
                                                     const int* __restrict__ dst,
                                                     int* __restrict__ fctr,
                                                     int2* __restrict__ recs2,
                                                     int e, int n) {
    __shared__ int lcnt[512], gbase[512];
    int tid = threadIdx.x;
    int s0  = blockIdx.x * BINTILE;
    lcnt[tid] = 0;
    lcnt[tid + 256] = 0;
    __syncthreads();
    int dv[16], bk[16];
#pragma unroll
    for (int k = 0; k < 16; ++k) {
        int i = s0 + tid + k * 256;  // coalesced
        if (i < e) {
            dv[k] = dst[i];
            bk[k] = (int)((512LL * dv[k]) / n);
            atomicAdd(&lcnt[bk[k]], 1);
        } else {
            bk[k] = -1;
        }
    }
    __syncthreads();
#pragma unroll
    for (int j = 0; j < 2; ++j) {
        int b = tid + j * 256;
        gbase[b] = b * CAPB + atomicAdd(&fctr[b], lcnt[b]);
        lcnt[b]  = 0;  // reuse as placement counter
    }
    __syncthreads();
#pragma unroll
    for (int k = 0; k < 16; ++k) {
        if (bk[k] >= 0) {
            int i = s0 + tid + k * 256;
            int p = gbase[bk[k]] + atomicAdd(&lcnt[bk[k]], 1);
            if (p < (bk[k] + 1) * CAPB) recs2[p] = make_int2(src[i], dv[k]);
        }
    }
}

// One block per fine bucket: LDS counting sort -> dense csr, rp/dinv, then
// fused mm1 for this bucket's nodes: t1 = fp16(dinv * x W1^T).
__global__ __launch_bounds__(256) void sortfill_mm_kernel(
    const int2* __restrict__ recs2, const int* __restrict__ fctr,
    int* __restrict__ rp, float* __restrict__ dinv, int* __restrict__ csr,
    const float* __restrict__ x, const float* __restrict__ W1,
    __half* __restrict__ t1, int n) {
    __shared__ int hist[128];
    __shared__ int lofs[129];
    __shared__ int stage[CAPB];
    __shared__ int redbuf[256];
    __shared__ float xrow[98 * 64];  // 25KB
    int g   = blockIdx.x;
    int N0  = (int)(((long long)n * g + 511) / 512);
    int N1  = (int)(((long long)n * (g + 1) + 511) / 512);
    int nn  = N1 - N0;  // <= 98
    int tid = threadIdx.x;
    int lane = tid & 63;
    int wave = tid >> 6;

    int partial = 0;
    for (int j = tid; j < g; j += 256) partial += min(fctr[j], CAPB);
    redbuf[tid] = partial;
    if (tid < 128) hist[tid] = 0;
    __syncthreads();
    for (int s = 128; s > 0; s >>= 1) {
        if (tid < s) redbuf[tid] += redbuf[tid + s];
        __syncthreads();
    }
    int base = redbuf[0];
    const int2* my = recs2 + (size_t)g * CAPB;
    int total = min(fctr[g], CAPB);
    for (int i = tid; i < total; i += 256)
        atomicAdd(&hist[my[i].y - N0], 1);
    __syncthreads();
    if (tid == 0) {
        int acc = 0;
        for (int k = 0; k < nn; ++k) { lofs[k] = acc; acc += hist[k]; }
        lofs[nn] = acc;
    }
    __syncthreads();
    if (tid < 128) hist[tid] = 0;  // placement counters
    __syncthreads();
    for (int i = tid; i < total; i += 256) {
        int2 rec = my[i];
        int  li  = rec.y - N0;
        int  pos = lofs[li] + atomicAdd(&hist[li], 1);
        stage[pos] = rec.x;  // pos < total <= CAPB
    }
    __syncthreads();
    for (int j = tid; j < total; j += 256) csr[base + j] = stage[j];
    if (tid < nn) {
        rp[N0 + tid]   = base + lofs[tid];
        int deg        = lofs[tid + 1] - lofs[tid];
        dinv[N0 + tid] = rsqrtf((float)(deg + 1));
    }
    if (g == 511 && tid == 0) rp[n] = base + total;

    // ---- fused mm1 for this bucket's nodes ----
    for (int idx = tid; idx < nn * 16; idx += 256)
        ((float4*)xrow)[idx] = ((const float4*)(x + (size_t)N0 * 64))[idx];
    float4 wreg[16];
    const float4* W4 = (const float4*)(W1 + lane * 64);
#pragma unroll
    for (int q = 0; q < 16; ++q) wreg[q] = W4[q];
    __syncthreads();
    for (int li = wave; li < nn; li += 4) {
        float dv = rsqrtf((float)(lofs[li + 1] - lofs[li] + 1));
        const float4* row = (const float4*)(xrow + li * 64);
        float acc = 0.0f;
#pragma unroll
        for (int q = 0; q < 16; ++q) {
            float4 hv = row[q];  // wave-uniform -> LDS broadcast
            acc += hv.x * wreg[q].x + hv.y * wreg[q].y +
                   hv.z * wreg[q].z + hv.w * wreg[q].w;
        }
        t1[(size_t)(N0 + li) * 64 + lane] = __float2half(acc * dv);
    }
}

// Fused agg(layer k) + mm(layer k+1). One wave per node (50000 waves, the
// R13/R18 invariant). Aggregation identical to the proven agg_kernel; then
// ALL lanes finalize h (the xor16/32 reduce already replicates the full row
// across the four 16-lane groups), and the wave computes its own node's
// t_out[i][lane] = dinv * h . W[lane] via readlane-broadcast of h chunks
// against a reg-resident W row, loaded in two halves to cap VGPR peak.
__global__ __launch_bounds__(256) void aggmm_kernel(const __half* __restrict__ t,
                                                    const int* __restrict__ rp,
                                                    const int* __restrict__ cs,
                                                    const float* __restrict__ dinv,
                                                    const float* __restrict__ bias,
                                                    const float* __restrict__ W,
                                                    __half* __restrict__ tout, int n) {
    int gw   = (blockIdx.x * blockDim.x + threadIdx.x) >> 6;
    int lane = threadIdx.x & 63;
    if (gw >= n) return;
    int i   = gw;
    int grp = lane >> 4;
    int fo  = (lane & 15) << 2;
    int beg = rp[i];
    int end = rp[i + 1];

    float4 a0 = make_float4(0.f, 0.f, 0.f, 0.f);
    float4 a1 = a0, a2 = a0, a3 = a0;
    int e = beg + grp;
    for (; e + 12 < end; e += 16) {
        int s0 = cs[e];
        int s1 = cs[e + 4];
        int s2 = cs[e + 8];
        int s3 = cs[e + 12];
        uint2 u0 = *(const uint2*)(t + (size_t)s0 * 64 + fo);
        uint2 u1 = *(const uint2*)(t + (size_t)s1 * 64 + fo);
        uint2 u2 = *(const uint2*)(t + (size_t)s2 * 64 + fo);
        uint2 u3 = *(const uint2*)(t + (size_t)s3 * 64 + fo);
        float2 f;
        f = __half22float2(*(const __half2*)&u0.x); a0.x += f.x; a0.y += f.y;
        f = __half22float2(*(const __half2*)&u0.y); a0.z += f.x; a0.w += f.y;
        f = __half22float2(*(const __half2*)&u1.x); a1.x += f.x; a1.y += f.y;
        f = __half22float2(*(const __half2*)&u1.y); a1.z += f.x; a1.w += f.y;
        f = __half22float2(*(const __half2*)&u2.x); a2.x += f.x; a2.y += f.y;
        f = __half22float2(*(const __half2*)&u2.y); a2.z += f.x; a2.w += f.y;
        f = __half22float2(*(const __half2*)&u3.x); a3.x += f.x; a3.y += f.y;
        f = __half22float2(*(const __half2*)&u3.y); a3.z += f.x; a3.w += f.y;
    }
    for (; e < end; e += 4) {
        int s = cs[e];
        uint2 u = *(const uint2*)(t + (size_t)s * 64 + fo);
        float2 f;
        f = __half22float2(*(const __half2*)&u.x); a1.x += f.x; a1.y += f.y;
        f = __half22float2(*(const __half2*)&u.y); a1.z += f.x; a1.w += f.y;
    }
    float4 acc;
    acc.x = (a0.x + a1.x) + (a2.x + a3.x);
    acc.y = (a0.y + a1.y) + (a2.y + a3.y);
    acc.z = (a0.z + a1.z) + (a2.z + a3.z);
    acc.w = (a0.w + a1.w) + (a2.w + a3.w);
    acc.x += __shfl_xor(acc.x, 16, 64);
    acc.y += __shfl_xor(acc.y, 16, 64);
    acc.z += __shfl_xor(acc.z, 16, 64);
    acc.w += __shfl_xor(acc.w, 16, 64);
    acc.x += __shfl_xor(acc.x, 32, 64);
    acc.y += __shfl_xor(acc.y, 32, 64);
    acc.z += __shfl_xor(acc.z, 32, 64);
    acc.w += __shfl_xor(acc.w, 32, 64);

    // all-lane finalize: every lane now holds h[i][4*(lane&15) .. +3]
    uint2 su = *(const uint2*)(t + (size_t)i * 64 + fo);
    float2 s01 = __half22float2(*(const __half2*)&su.x);
    float2 s23 = __half22float2(*(const __half2*)&su.y);
    float4 bv = *(const float4*)(bias + fo);
    float  dv = dinv[i];
    float4 h4;
    h4.x = fmaxf(fmaf(dv, acc.x + s01.x, bv.x), 0.0f);
    h4.y = fmaxf(fmaf(dv, acc.y + s01.y, bv.y), 0.0f);
    h4.z = fmaxf(fmaf(dv, acc.z + s23.x, bv.z), 0.0f);
    h4.w = fmaxf(fmaf(dv, acc.w + s23.y, bv.w), 0.0f);

    // in-wave matvec: lane owns output column 'lane'. Two 8-chunk halves,
    // fenced so W loads don't hoist into the gather loop (VGPR peak cap).
    const float4* W4 = (const float4*)(W + lane * 64);
    float om = 0.0f;
    __builtin_amdgcn_sched_barrier(0);
    {
        float4 wreg[8];
#pragma unroll
        for (int q = 0; q < 8; ++q) wreg[q] = W4[q];
#pragma unroll
        for (int c = 0; c < 8; ++c) {
            om = fmaf(rl_f(h4.x, c), wreg[c].x, om);
            om = fmaf(rl_f(h4.y, c), wreg[c].y, om);
            om = fmaf(rl_f(h4.z, c), wreg[c].z, om);
            om = fmaf(rl_f(h4.w, c), wreg[c].w, om);
        }
    }
    __builtin_amdgcn_sched_barrier(0);
    {
        float4 wreg[8];
#pragma unroll
        for (int q = 0; q < 8; ++q) wreg[q] = W4[8 + q];
#pragma unroll
        for (int c = 0; c < 8; ++c) {
            om = fmaf(rl_f(h4.x, c + 8), wreg[c].x, om);
            om = fmaf(rl_f(h4.y, c + 8), wreg[c].y, om);
            om = fmaf(rl_f(h4.z, c + 8), wreg[c].z, om);
            om = fmaf(rl_f(h4.w, c + 8), wreg[c].w, om);
        }
    }
    tout[(size_t)i * 64 + lane] = __float2half(om * dv);
}

// Final layer: agg -> h3 (all lanes) -> per-node z = h3 . Wl^T with
// chunk-aligned Wl fragments (lane's own h chunk c=lane&15, outputs
// o = 4m + (lane>>4), m=0..3; 16 regs), xor-reduce over chunks, then 16
// atomicAdds of z*inv_cnt into out (pre-seeded with bl by init_kernel).
__global__ __launch_bounds__(256) void aggfinal_kernel(const __half* __restrict__ t,
                                                       const int* __restrict__ rp,
                                                       const int* __restrict__ cs,
                                                       const float* __restrict__ dinv,
                                                       const float* __restrict__ bias,
                                                       const float* __restrict__ Wl,
                                                       const int* __restrict__ batch,
                                                       const float* __restrict__ invc,
                                                       float* __restrict__ out, int n) {
    int gw   = (blockIdx.x * blockDim.x + threadIdx.x) >> 6;
    int lane = threadIdx.x & 63;
    if (gw >= n) return;
    int i   = gw;
    int grp = lane >> 4;
    int fo  = (lane & 15) << 2;
    int beg = rp[i];
    int end = rp[i + 1];

    float4 a0 = make_float4(0.f, 0.f, 0.f, 0.f);
    float4 a1 = a0, a2 = a0, a3 = a0;
    int e = beg + grp;
    for (; e + 12 < end; e += 16) {
        int s0 = cs[e];
        int s1 = cs[e + 4];
        int s2 = cs[e + 8];
        int s3 = cs[e + 12];
        uint2 u0 = *(const uint2*)(t + (size_t)s0 * 64 + fo);
        uint2 u1 = *(const uint2*)(t + (size_t)s1 * 64 + fo);
        uint2 u2 = *(const uint2*)(t + (size_t)s2 * 64 + fo);
        uint2 u3 = *(const uint2*)(t + (size_t)s3 * 64 + fo);
        float2 f;
        f = __half22float2(*(const __half2*)&u0.x); a0.x += f.x; a0.y += f.y;
        f = __half22float2(*(const __half2*)&u0.y); a0.z += f.x; a0.w += f.y;
        f = __half22float2(*(const __half2*)&u1.x); a1.x += f.x; a1.y += f.y;
        f = __half22float2(*(const __half2*)&u1.y); a1.z += f.x; a1.w += f.y;
        f = __half22float2(*(const __half2*)&u2.x); a2.x += f.x; a2.y += f.y;
        f = __half22float2(*(const __half2*)&u2.y); a2.z += f.x; a2.w += f.y;
        f = __half22float2(*(const __half2*)&u3.x); a3.x += f.x; a3.y += f.y;
        f = __half22float2(*(const __half2*)&u3.y); a3.z += f.x; a3.w += f.y;
    }
    for (; e < end; e += 4) {
        int s = cs[e];
        uint2 u = *(const uint2*)(t + (size_t)s * 64 + fo);
        float2 f;
        f = __half22float2(*(const __half2*)&u.x); a1.x += f.x; a1.y += f.y;
        f = __half22float2(*(const __half2*)&u.y); a1.z += f.x; a1.w += f.y;
    }
    float4 acc;
    acc.x = (a0.x + a1.x) + (a2.x + a3.x);
    acc.y = (a0.y + a1.y) + (a2.y + a3.y);
    acc.z = (a0.z + a1.z) + (a2.z + a3.z);
    acc.w = (a0.w + a1.w) + (a2.w + a3.w);
    acc.x += __shfl_xor(acc.x, 16, 64);
    acc.y += __shfl_xor(acc.y, 16, 64);
    acc.z += __shfl_xor(acc.z, 16, 64);
    acc.w += __shfl_xor(acc.w, 16, 64);
    acc.x += __shfl_xor(acc.x, 32, 64);
    acc.y += __shfl_xor(acc.y, 32, 64);
    acc.z += __shfl_xor(acc.z, 32, 64);
    acc.w += __shfl_xor(acc.w, 32, 64);

    uint2 su = *(const uint2*)(t + (size_t)i * 64 + fo);
    float2 s01 = __half22float2(*(const __half2*)&su.x);
    float2 s23 = __half22float2(*(const __half2*)&su.y);
    float4 bv = *(const float4*)(bias + fo);
    float  dv = dinv[i];
    float4 h4;
    h4.x = fmaxf(fmaf(dv, acc.x + s01.x, bv.x), 0.0f);
    h4.y = fmaxf(fmaf(dv, acc.y + s01.y, bv.y), 0.0f);
    h4.z = fmaxf(fmaf(dv, acc.z + s23.x, bv.z), 0.0f);
    h4.w = fmaxf(fmaf(dv, acc.w + s23.y, bv.w), 0.0f);

    // z[o] = h3 . Wl[o], o = 4m + grp; lane uses only its own chunk.
    __builtin_amdgcn_sched_barrier(0);
    float4 wl0 = *(const float4*)(Wl + (0 * 4 + grp) * 64 + fo);
    float4 wl1 = *(const float4*)(Wl + (1 * 4 + grp) * 64 + fo);
    float4 wl2 = *(const float4*)(Wl + (2 * 4 + grp) * 64 + fo);
    float4 wl3 = *(const float4*)(Wl + (3 * 4 + grp) * 64 + fo);
    float z0 = h4.x * wl0.x + h4.y * wl0.y + h4.z * wl0.z + h4.w * wl0.w;
    float z1 = h4.x * wl1.x + h4.y * wl1.y + h4.z * wl1.z + h4.w * wl1.w;
    float z2 = h4.x * wl2.x + h4.y * wl2.y + h4.z * wl2.z + h4.w * wl2.w;
    float z3 = h4.x * wl3.x + h4.y * wl3.y + h4.z * wl3.z + h4.w * wl3.w;
#pragma unroll
    for (int s = 1; s <= 8; s <<= 1) {
        z0 += __shfl_xor(z0, s, 64);
        z1 += __shfl_xor(z1, s, 64);
        z2 += __shfl_xor(z2, s, 64);
        z3 += __shfl_xor(z3, s, 64);
    }
    int m = lane & 15;
    if (m < 4) {
        int   b  = batch[i];
        float ic = invc[b];
        float zv = (m == 0) ? z0 : (m == 1) ? z1 : (m == 2) ? z2 : z3;
        atomicAdd(out + b * 16 + (m * 4 + grp), zv * ic);
    }
}

extern "C" void kernel_launch(void* const* d_in, const int* in_sizes, int n_in,
                              void* d_out, int out_size, void* d_ws, size_t ws_size,
                              hipStream_t stream) {
    const float* x    = (const float*)d_in[0];
    const int*   ei   = (const int*)d_in[1];
    const int*   batch= (const int*)d_in[2];
    const float* W1   = (const float*)d_in[3];
    const float* b1   = (const float*)d_in[4];
    const float* W2   = (const float*)d_in[5];
    const float* b2   = (const float*)d_in[6];
    const float* W3   = (const float*)d_in[7];
    const float* b3   = (const float*)d_in[8];
    const float* Wl   = (const float*)d_in[9];
    const float* bl   = (const float*)d_in[10];
    float* out = (float*)d_out;

    int n  = in_sizes[0] / 64;   // 50000 nodes
    int e  = in_sizes[1] / 2;    // 1250000 edges
    int nb = out_size / 16;      // 512 graphs

    const int* esrc = ei;
    const int* edst = ei + e;

    char* p = (char*)d_ws;
    auto carve = [&](size_t bytes) {
        char* r = p;
        p += (bytes + 255) & ~(size_t)255;
        return r;
    };
    float*  dinv  = (float*)carve((size_t)n * 4);
    int*    rp    = (int*)  carve((size_t)(n + 1) * 4);
    int*    csr   = (int*)  carve((size_t)e * 4);
    __half* tA    = (__half*)carve((size_t)n * 64 * 2);  // t1 / t3
    __half* tB    = (__half*)carve((size_t)n * 64 * 2);  // t2
    int2*   recs2 = (int2*) carve((size_t)512 * CAPB * 8);
    int*    fctr  = (int*)  carve(512 * 4);
    float*  invc  = (float*)carve((size_t)nb * 4);

    dim3 blk(256);
    int gBIN = (e + BINTILE - 1) / BINTILE;  // 306 tiles
    int gAGG = (n + 3) / 4;                  // one node per wave

    init_kernel<<<2, blk, 0, stream>>>(fctr, batch, bl, invc, out, n, nb);
    bin512_kernel<<<gBIN, blk, 0, stream>>>(esrc, edst, fctr, recs2, e, n);
    sortfill_mm_kernel<<<512, blk, 0, stream>>>(recs2, fctr, rp, dinv, csr,
                                                x, W1, tA, n);
    aggmm_kernel<<<gAGG, blk, 0, stream>>>(tA, rp, csr, dinv, b1, W2, tB, n);
    aggmm_kernel<<<gAGG, blk, 0, stream>>>(tB, rp, csr, dinv, b2, W3, tA, n);
    aggfinal_kernel<<<gAGG, blk, 0, stream>>>(tA, rp, csr, dinv, b3, Wl,
                                              batch, invc, out, n);
}

// Round 2
// 288.195 us; speedup vs baseline: 1.3903x; 1.3903x over previous
//
#include <hip/hip_runtime.h>
#include <hip/hip_fp16.h>

// ---------------------------------------------------------------------------
// GCN (3 layers) + global mean pool + linear, fp32 in/out, MI355X.
// t'[i] = dinv[i] * h[i] W^T; h_next[i] = relu(dinv[i]*(t'[i]+sum t'[j]) + b)
// R3-R5: scattered 4B global stores/atomics = ~32B HBM sector each. Dense only.
// R9: fp16 t (128B row = 1 L2 line), absmax 1.2e-4.
// R13/R18/R20 (counter-verified): fusing mm into agg fails at EVERY
//   granularity. R20 per-wave matvec: VGPR=28 (compiler won't hold W frags),
//   -> 16 serial L2 loads/wave tail, 113us vs 45us. W must be amortized over
//   a 64-node block (mm_kernel) and agg must keep 1 node/wave (50000 waves).
// R16/R17: cooperative persistent kernel dead (not capturable).
// R14: ~13us/launch gap -> launch count matters: 8 launches here.
// R19: sortfill_mm fusion works (matched 512-block granularity).
// R20 keepers: aggfinal (agg3+pool+linear, chunk-parallel Wl + atomics into
//   bl-seeded out) and init computing invc. Both passed, absmax 1.2e-4.
// R21 (this round): 8-wide masked-parallel gather. Old: 4-deep unroll + ~2
//   SERIAL remainder gathers/group (~1200cyc tail/wave). New: each group owns
//   a contiguous deg/4 slice, issues 8 index-clamped gathers per round,
//   mask-FMA accumulate (branchless). launch_bounds(256,6) caps VGPR ~85.
// ---------------------------------------------------------------------------

#define CAPB 3072
#define BINTILE 4096

// fctr zero + per-graph inverse counts (binary search on sorted batch) +
// out seeded with bl (aggfinal accumulates atomically on top).
__global__ __launch_bounds__(256) void init_kernel(int* __restrict__ fctr,
                                                   const int* __restrict__ batch,
                                                   const float* __restrict__ bl,
                                                   float* __restrict__ invc,
                                                   float* __restrict__ out,
                                                   int n, int nb) {
    int t = blockIdx.x * blockDim.x + threadIdx.x;
    if (t < 512) fctr[t] = 0;
    if (t < nb) {
        int l = 0, r = n;
        while (l < r) { int m = (l + r) >> 1; if (batch[m] < t) l = m + 1; else r = m; }
        int lo = l;
        r = n;
        while (l < r) { int m = (l + r) >> 1; if (batch[m] < t + 1) l = m + 1; else r = m; }
        invc[t] = 1.0f / fmaxf((float)(l - lo), 1.0f);
#pragma unroll
        for (int o = 0; o < 16; ++o) out[t * 16 + o] = bl[o];
    }
}

// Bucket edges into 512 fine dst-ranges (fixed capacity CAPB, base=g*CAPB).
__global__ __launch_bounds__(256) void bin512_kernel(const int* __restrict__ src,
                                                     const int* __restrict__ dst,
                                                     int* __restrict__ fctr,
                                                     int2* __restrict__ recs2,
                                                     int e, int n) {
    __shared__ int lcnt[512], gbase[512];
    int tid = threadIdx.x;
    int s0  = blockIdx.x * BINTILE;
    lcnt[tid] = 0;
    lcnt[tid + 256] = 0;
    __syncthreads();
    int dv[16], bk[16];
#pragma unroll
    for (int k = 0; k < 16; ++k) {
        int i = s0 + tid + k * 256;  // coalesced
        if (i < e) {
            dv[k] = dst[i];
            bk[k] = (int)((512LL * dv[k]) / n);
            atomicAdd(&lcnt[bk[k]], 1);
        } else {
            bk[k] = -1;
        }
    }
    __syncthreads();
#pragma unroll
    for (int j = 0; j < 2; ++j) {
        int b = tid + j * 256;
        gbase[b] = b * CAPB + atomicAdd(&fctr[b], lcnt[b]);
        lcnt[b]  = 0;  // reuse as placement counter
    }
    __syncthreads();
#pragma unroll
    for (int k = 0; k < 16; ++k) {
        if (bk[k] >= 0) {
            int i = s0 + tid + k * 256;
            int p = gbase[bk[k]] + atomicAdd(&lcnt[bk[k]], 1);
            if (p < (bk[k] + 1) * CAPB) recs2[p] = make_int2(src[i], dv[k]);
        }
    }
}

// One block per fine bucket: LDS counting sort -> dense csr, rp/dinv, then
// fused mm1 for this bucket's nodes: t1 = fp16(dinv * x W1^T).
__global__ __launch_bounds__(256) void sortfill_mm_kernel(
    const int2* __restrict__ recs2, const int* __restrict__ fctr,
    int* __restrict__ rp, float* __restrict__ dinv, int* __restrict__ csr,
    const float* __restrict__ x, const float* __restrict__ W1,
    __half* __restrict__ t1, int n) {
    __shared__ int hist[128];
    __shared__ int lofs[129];
    __shared__ int stage[CAPB];
    __shared__ int redbuf[256];
    __shared__ float xrow[98 * 64];  // 25KB
    int g   = blockIdx.x;
    int N0  = (int)(((long long)n * g + 511) / 512);
    int N1  = (int)(((long long)n * (g + 1) + 511) / 512);
    int nn  = N1 - N0;  // <= 98
    int tid = threadIdx.x;
    int lane = tid & 63;
    int wave = tid >> 6;

    int partial = 0;
    for (int j = tid; j < g; j += 256) partial += min(fctr[j], CAPB);
    redbuf[tid] = partial;
    if (tid < 128) hist[tid] = 0;
    __syncthreads();
    for (int s = 128; s > 0; s >>= 1) {
        if (tid < s) redbuf[tid] += redbuf[tid + s];
        __syncthreads();
    }
    int base = redbuf[0];
    const int2* my = recs2 + (size_t)g * CAPB;
    int total = min(fctr[g], CAPB);
    for (int i = tid; i < total; i += 256)
        atomicAdd(&hist[my[i].y - N0], 1);
    __syncthreads();
    if (tid == 0) {
        int acc = 0;
        for (int k = 0; k < nn; ++k) { lofs[k] = acc; acc += hist[k]; }
        lofs[nn] = acc;
    }
    __syncthreads();
    if (tid < 128) hist[tid] = 0;  // placement counters
    __syncthreads();
    for (int i = tid; i < total; i += 256) {
        int2 rec = my[i];
        int  li  = rec.y - N0;
        int  pos = lofs[li] + atomicAdd(&hist[li], 1);
        stage[pos] = rec.x;  // pos < total <= CAPB
    }
    __syncthreads();
    for (int j = tid; j < total; j += 256) csr[base + j] = stage[j];
    if (tid < nn) {
        rp[N0 + tid]   = base + lofs[tid];
        int deg        = lofs[tid + 1] - lofs[tid];
        dinv[N0 + tid] = rsqrtf((float)(deg + 1));
    }
    if (g == 511 && tid == 0) rp[n] = base + total;

    // ---- fused mm1 for this bucket's nodes ----
    for (int idx = tid; idx < nn * 16; idx += 256)
        ((float4*)xrow)[idx] = ((const float4*)(x + (size_t)N0 * 64))[idx];
    float4 wreg[16];
    const float4* W4 = (const float4*)(W1 + lane * 64);
#pragma unroll
    for (int q = 0; q < 16; ++q) wreg[q] = W4[q];
    __syncthreads();
    for (int li = wave; li < nn; li += 4) {
        float dv = rsqrtf((float)(lofs[li + 1] - lofs[li] + 1));
        const float4* row = (const float4*)(xrow + li * 64);
        float acc = 0.0f;
#pragma unroll
        for (int q = 0; q < 16; ++q) {
            float4 hv = row[q];  // wave-uniform -> LDS broadcast
            acc += hv.x * wreg[q].x + hv.y * wreg[q].y +
                   hv.z * wreg[q].z + hv.w * wreg[q].w;
        }
        t1[(size_t)(N0 + li) * 64 + lane] = __float2half(acc * dv);
    }
}

// t[i][o] = fp16( dinv[i] * sum_k h[i][k] * W[o][k] )  (layers 2,3)
// 256 thr = 4 waves; 64 nodes/block. W row per lane in 16 float4 regs;
// 64 h-rows staged in LDS, read as broadcast float4. Row store = dense 128B.
__global__ __launch_bounds__(256) void mm_kernel(const float* __restrict__ h,
                                                 const float* __restrict__ W,
                                                 const float* __restrict__ dinv,
                                                 __half* __restrict__ t, int n) {
    __shared__ float hs[64 * 64];
    int tid  = threadIdx.x;
    int lane = tid & 63;
    int wave = tid >> 6;
    int base = blockIdx.x * 64;

    float4 wreg[16];
    const float4* W4 = (const float4*)(W + lane * 64);
#pragma unroll
    for (int q = 0; q < 16; ++q) wreg[q] = W4[q];

    int nrows = min(64, n - base);
    const float4* h4  = (const float4*)(h + (size_t)base * 64);
    float4*       hs4 = (float4*)hs;
    for (int idx = tid; idx < nrows * 16; idx += 256) hs4[idx] = h4[idx];
    __syncthreads();

    for (int r = wave * 16; r < wave * 16 + 16; ++r) {
        int i = base + r;
        if (i >= n) break;
        const float4* row = (const float4*)(hs + r * 64);
        float acc = 0.0f;
#pragma unroll
        for (int q = 0; q < 16; ++q) {
            float4 hv = row[q];  // wave-uniform address -> LDS broadcast
            acc += hv.x * wreg[q].x + hv.y * wreg[q].y +
                   hv.z * wreg[q].z + hv.w * wreg[q].w;
        }
        t[(size_t)i * 64 + lane] = __float2half(acc * dinv[i]);
    }
}

// One wave per node (50000 waves). 4 groups x 16 feature-lanes; each group
// owns a CONTIGUOUS deg/4 slice and issues 8 index-clamped gathers per
// round (branchless mask-FMA) -> one cs-round + one t-round of latency for
// deg<=32 nodes (93%). shfl_xor(16,32) reduce; grp0 dense 256B store.
__global__ __launch_bounds__(256, 6) void agg_kernel(const __half* __restrict__ t,
                                                     const int* __restrict__ rp,
                                                     const int* __restrict__ cs,
                                                     const float* __restrict__ dinv,
                                                     const float* __restrict__ bias,
                                                     float* __restrict__ hout, int n) {
    int gw   = (blockIdx.x * blockDim.x + threadIdx.x) >> 6;
    int lane = threadIdx.x & 63;
    if (gw >= n) return;
    int i   = gw;
    int grp = lane >> 4;
    int fo  = (lane & 15) << 2;
    int beg = rp[i];
    int end = rp[i + 1];
    // independent loads issued early
    uint2 su = *(const uint2*)(t + (size_t)i * 64 + fo);
    float dv = dinv[i];
    float4 bv = *(const float4*)(bias + fo);

    int deg = end - beg;
    int len = (deg + 3) >> 2;       // per-group slice length
    int gb  = beg + grp * len;
    int ge  = min(gb + len, end);

    float4 aa[4];
    aa[0] = make_float4(0.f, 0.f, 0.f, 0.f);
    aa[1] = aa[0]; aa[2] = aa[0]; aa[3] = aa[0];
    for (int eb = gb; eb < ge; eb += 8) {
#pragma unroll
        for (int j = 0; j < 8; ++j) {
            int   ej = eb + j;
            int   ec = min(ej, end - 1);            // always in csr bounds (deg>=1)
            int   sj = cs[ec];                      // unconditional load
            uint2 u  = *(const uint2*)(t + (size_t)sj * 64 + fo);
            float m  = (ej < ge) ? 1.0f : 0.0f;
            float2 f0 = __half22float2(*(const __half2*)&u.x);
            float2 f1 = __half22float2(*(const __half2*)&u.y);
            aa[j & 3].x = fmaf(m, f0.x, aa[j & 3].x);
            aa[j & 3].y = fmaf(m, f0.y, aa[j & 3].y);
            aa[j & 3].z = fmaf(m, f1.x, aa[j & 3].z);
            aa[j & 3].w = fmaf(m, f1.y, aa[j & 3].w);
        }
    }
    float4 acc;
    acc.x = (aa[0].x + aa[1].x) + (aa[2].x + aa[3].x);
    acc.y = (aa[0].y + aa[1].y) + (aa[2].y + aa[3].y);
    acc.z = (aa[0].z + aa[1].z) + (aa[2].z + aa[3].z);
    acc.w = (aa[0].w + aa[1].w) + (aa[2].w + aa[3].w);
    acc.x += __shfl_xor(acc.x, 16, 64);
    acc.y += __shfl_xor(acc.y, 16, 64);
    acc.z += __shfl_xor(acc.z, 16, 64);
    acc.w += __shfl_xor(acc.w, 16, 64);
    acc.x += __shfl_xor(acc.x, 32, 64);
    acc.y += __shfl_xor(acc.y, 32, 64);
    acc.z += __shfl_xor(acc.z, 32, 64);
    acc.w += __shfl_xor(acc.w, 32, 64);
    if (grp == 0) {
        float2 s01 = __half22float2(*(const __half2*)&su.x);
        float2 s23 = __half22float2(*(const __half2*)&su.y);
        float4 o;
        o.x = fmaxf(fmaf(dv, acc.x + s01.x, bv.x), 0.0f);
        o.y = fmaxf(fmaf(dv, acc.y + s01.y, bv.y), 0.0f);
        o.z = fmaxf(fmaf(dv, acc.z + s23.x, bv.z), 0.0f);
        o.w = fmaxf(fmaf(dv, acc.w + s23.y, bv.w), 0.0f);
        *(float4*)(hout + (size_t)i * 64 + fo) = o;
    }
}

// Final layer: same 8-wide gather -> h3 on all lanes -> per-node
// z = h3 . Wl^T with chunk-aligned Wl fragments (lane's own chunk c=lane&15,
// outputs o = 4m + grp, 4 parallel float4 loads), xor-reduce over chunks,
// then 16 atomicAdds of z*inv_cnt into out (pre-seeded with bl).
__global__ __launch_bounds__(256, 6) void aggfinal_kernel(const __half* __restrict__ t,
                                                          const int* __restrict__ rp,
                                                          const int* __restrict__ cs,
                                                          const float* __restrict__ dinv,
                                                          const float* __restrict__ bias,
                                                          const float* __restrict__ Wl,
                                                          const int* __restrict__ batch,
                                                          const float* __restrict__ invc,
                                                          float* __restrict__ out, int n) {
    int gw   = (blockIdx.x * blockDim.x + threadIdx.x) >> 6;
    int lane = threadIdx.x & 63;
    if (gw >= n) return;
    int i   = gw;
    int grp = lane >> 4;
    int fo  = (lane & 15) << 2;
    int beg = rp[i];
    int end = rp[i + 1];
    uint2 su = *(const uint2*)(t + (size_t)i * 64 + fo);
    float dv = dinv[i];
    float4 bv = *(const float4*)(bias + fo);

    int deg = end - beg;
    int len = (deg + 3) >> 2;
    int gb  = beg + grp * len;
    int ge  = min(gb + len, end);

    float4 aa[4];
    aa[0] = make_float4(0.f, 0.f, 0.f, 0.f);
    aa[1] = aa[0]; aa[2] = aa[0]; aa[3] = aa[0];
    for (int eb = gb; eb < ge; eb += 8) {
#pragma unroll
        for (int j = 0; j < 8; ++j) {
            int   ej = eb + j;
            int   ec = min(ej, end - 1);
            int   sj = cs[ec];
            uint2 u  = *(const uint2*)(t + (size_t)sj * 64 + fo);
            float m  = (ej < ge) ? 1.0f : 0.0f;
            float2 f0 = __half22float2(*(const __half2*)&u.x);
            float2 f1 = __half22float2(*(const __half2*)&u.y);
            aa[j & 3].x = fmaf(m, f0.x, aa[j & 3].x);
            aa[j & 3].y = fmaf(m, f0.y, aa[j & 3].y);
            aa[j & 3].z = fmaf(m, f1.x, aa[j & 3].z);
            aa[j & 3].w = fmaf(m, f1.y, aa[j & 3].w);
        }
    }
    float4 acc;
    acc.x = (aa[0].x + aa[1].x) + (aa[2].x + aa[3].x);
    acc.y = (aa[0].y + aa[1].y) + (aa[2].y + aa[3].y);
    acc.z = (aa[0].z + aa[1].z) + (aa[2].z + aa[3].z);
    acc.w = (aa[0].w + aa[1].w) + (aa[2].w + aa[3].w);
    acc.x += __shfl_xor(acc.x, 16, 64);
    acc.y += __shfl_xor(acc.y, 16, 64);
    acc.z += __shfl_xor(acc.z, 16, 64);
    acc.w += __shfl_xor(acc.w, 16, 64);
    acc.x += __shfl_xor(acc.x, 32, 64);
    acc.y += __shfl_xor(acc.y, 32, 64);
    acc.z += __shfl_xor(acc.z, 32, 64);
    acc.w += __shfl_xor(acc.w, 32, 64);

    // all lanes hold h3[i][4*(lane&15) .. +3]
    float2 s01 = __half22float2(*(const __half2*)&su.x);
    float2 s23 = __half22float2(*(const __half2*)&su.y);
    float4 h4;
    h4.x = fmaxf(fmaf(dv, acc.x + s01.x, bv.x), 0.0f);
    h4.y = fmaxf(fmaf(dv, acc.y + s01.y, bv.y), 0.0f);
    h4.z = fmaxf(fmaf(dv, acc.z + s23.x, bv.z), 0.0f);
    h4.w = fmaxf(fmaf(dv, acc.w + s23.y, bv.w), 0.0f);

    // z[o] = h3 . Wl[o], o = 4m + grp; lane uses only its own chunk.
    float4 wl0 = *(const float4*)(Wl + (0 * 4 + grp) * 64 + fo);
    float4 wl1 = *(const float4*)(Wl + (1 * 4 + grp) * 64 + fo);
    float4 wl2 = *(const float4*)(Wl + (2 * 4 + grp) * 64 + fo);
    float4 wl3 = *(const float4*)(Wl + (3 * 4 + grp) * 64 + fo);
    float z0 = h4.x * wl0.x + h4.y * wl0.y + h4.z * wl0.z + h4.w * wl0.w;
    float z1 = h4.x * wl1.x + h4.y * wl1.y + h4.z * wl1.z + h4.w * wl1.w;
    float z2 = h4.x * wl2.x + h4.y * wl2.y + h4.z * wl2.z + h4.w * wl2.w;
    float z3 = h4.x * wl3.x + h4.y * wl3.y + h4.z * wl3.z + h4.w * wl3.w;
#pragma unroll
    for (int s = 1; s <= 8; s <<= 1) {
        z0 += __shfl_xor(z0, s, 64);
        z1 += __shfl_xor(z1, s, 64);
        z2 += __shfl_xor(z2, s, 64);
        z3 += __shfl_xor(z3, s, 64);
    }
    int m = lane & 15;
    if (m < 4) {
        int   b  = batch[i];
        float ic = invc[b];
        float zv = (m == 0) ? z0 : (m == 1) ? z1 : (m == 2) ? z2 : z3;
        atomicAdd(out + b * 16 + (m * 4 + grp), zv * ic);
    }
}

extern "C" void kernel_launch(void* const* d_in, const int* in_sizes, int n_in,
                              void* d_out, int out_size, void* d_ws, size_t ws_size,
                              hipStream_t stream) {
    const float* x    = (const float*)d_in[0];
    const int*   ei   = (const int*)d_in[1];
    const int*   batch= (const int*)d_in[2];
    const float* W1   = (const float*)d_in[3];
    const float* b1   = (const float*)d_in[4];
    const float* W2   = (const float*)d_in[5];
    const float* b2   = (const float*)d_in[6];
    const float* W3   = (const float*)d_in[7];
    const float* b3   = (const float*)d_in[8];
    const float* Wl   = (const float*)d_in[9];
    const float* bl   = (const float*)d_in[10];
    float* out = (float*)d_out;

    int n  = in_sizes[0] / 64;   // 50000 nodes
    int e  = in_sizes[1] / 2;    // 1250000 edges
    int nb = out_size / 16;      // 512 graphs

    const int* esrc = ei;
    const int* edst = ei + e;

    char* p = (char*)d_ws;
    auto carve = [&](size_t bytes) {
        char* r = p;
        p += (bytes + 255) & ~(size_t)255;
        return r;
    };
    size_t featBytes = (size_t)n * 64 * 4;     // 12.80 MB (fp32 h)
    size_t recsBytes = (size_t)512 * CAPB * 8; // 12.58 MB recs2
    size_t bufBBytes = recsBytes > featBytes ? recsBytes : featBytes;

    float*  dinv = (float*)carve((size_t)n * 4);
    int*    rp   = (int*)  carve((size_t)(n + 1) * 4);
    int*    csr  = (int*)  carve((size_t)e * 4);
    __half* bufT = (__half*)carve((size_t)n * 64 * 2);  // fp16 t (6.4 MB)
    float*  bufB = (float*)carve(bufBBytes);            // recs2, then h
    int*    fctr = (int*)  carve(512 * 4);
    float*  invc = (float*)carve((size_t)nb * 4);
    int2*   recs2 = (int2*)bufB;  // dead before agg1 writes bufB

    dim3 blk(256);
    int gBIN = (e + BINTILE - 1) / BINTILE;  // 306 tiles
    int gMM  = (n + 63) / 64;
    int gAGG = (n + 3) / 4;                  // one node per wave

    init_kernel<<<2, blk, 0, stream>>>(fctr, batch, bl, invc, out, n, nb);
    bin512_kernel<<<gBIN, blk, 0, stream>>>(esrc, edst, fctr, recs2, e, n);
    sortfill_mm_kernel<<<512, blk, 0, stream>>>(recs2, fctr, rp, dinv, csr,
                                                x, W1, bufT, n);
    agg_kernel<<<gAGG, blk, 0, stream>>>(bufT, rp, csr, dinv, b1, bufB, n);
    mm_kernel<<<gMM, blk, 0, stream>>>(bufB, W2, dinv, bufT, n);
    agg_kernel<<<gAGG, blk, 0, stream>>>(bufT, rp, csr, dinv, b2, bufB, n);
    mm_kernel<<<gMM, blk, 0, stream>>>(bufB, W3, dinv, bufT, n);
    aggfinal_kernel<<<gAGG, blk, 0, stream>>>(bufT, rp, csr, dinv, b3, Wl,
                                              batch, invc, out, n);
}

// Round 3
// 287.175 us; speedup vs baseline: 1.3952x; 1.0036x over previous
//
#include <hip/hip_runtime.h>
#include <hip/hip_fp16.h>

// ---------------------------------------------------------------------------
// GCN (3 layers) + global mean pool + linear, fp32 in/out, MI355X.
// t'[i] = dinv[i] * h[i] W^T; h_next[i] = relu(dinv[i]*(t'[i]+sum t'[j]) + b)
// R3-R5: scattered 4B global stores/atomics = ~32B HBM sector each. Dense only.
// R9: fp16 t (128B row = 1 L2 line), absmax 1.2e-4.
// R13/R18/R20 (counter-verified): agg+mm fusion fails if it (a) cuts gather
//   MLP (R18: 8 nodes SERIAL per wave, occ 30%) or (b) leaves W unamortized
//   per wave (R20: VGPR=28, serial W reloads, 113us).
// R21: 8-wide masked-parallel gather (+20us); aggfinal fuses agg3+pool+linear.
// R22 (this round): aggmm fusion satisfying BOTH constraints: 512-thr/32-node
//   blocks, one node per 16-lane GROUP (lane owns 4 features exclusively ->
//   no shfl reduce), 8-deep clamped gather => 4 independent nodes/wave, 32
//   loads in flight (MLP/wave x4 compensates 12500 vs 50000 waves). Then
//   syncthreads + PROVEN mm_kernel body (LDS h rows, W row/lane in 16 float4
//   regs, 4 rows/wave). launch_bounds(512,4) caps VGPR 128 (no spill).
//   8 -> 6 launches; fp32 h round-trip (51MB HBM) eliminated.
// ---------------------------------------------------------------------------

#define CAPB 3072
#define BINTILE 4096

// fctr zero + per-graph inverse counts (binary search on sorted batch) +
// out seeded with bl (aggfinal accumulates atomically on top).
__global__ __launch_bounds__(256) void init_kernel(int* __restrict__ fctr,
                                                   const int* __restrict__ batch,
                                                   const float* __restrict__ bl,
                                                   float* __restrict__ invc,
                                                   float* __restrict__ out,
                                                   int n, int nb) {
    int t = blockIdx.x * blockDim.x + threadIdx.x;
    if (t < 512) fctr[t] = 0;
    if (t < nb) {
        int l = 0, r = n;
        while (l < r) { int m = (l + r) >> 1; if (batch[m] < t) l = m + 1; else r = m; }
        int lo = l;
        r = n;
        while (l < r) { int m = (l + r) >> 1; if (batch[m] < t + 1) l = m + 1; else r = m; }
        invc[t] = 1.0f / fmaxf((float)(l - lo), 1.0f);
#pragma unroll
        for (int o = 0; o < 16; ++o) out[t * 16 + o] = bl[o];
    }
}

// Bucket edges into 512 fine dst-ranges (fixed capacity CAPB, base=g*CAPB).
__global__ __launch_bounds__(256) void bin512_kernel(const int* __restrict__ src,
                                                     const int* __restrict__ dst,
                                                     int* __restrict__ fctr,
                                                     int2* __restrict__ recs2,
                                                     int e, int n) {
    __shared__ int lcnt[512], gbase[512];
    int tid = threadIdx.x;
    int s0  = blockIdx.x * BINTILE;
    lcnt[tid] = 0;
    lcnt[tid + 256] = 0;
    __syncthreads();
    int dv[16], bk[16];
#pragma unroll
    for (int k = 0; k < 16; ++k) {
        int i = s0 + tid + k * 256;  // coalesced
        if (i < e) {
            dv[k] = dst[i];
            bk[k] = (int)((512LL * dv[k]) / n);
            atomicAdd(&lcnt[bk[k]], 1);
        } else {
            bk[k] = -1;
        }
    }
    __syncthreads();
#pragma unroll
    for (int j = 0; j < 2; ++j) {
        int b = tid + j * 256;
        gbase[b] = b * CAPB + atomicAdd(&fctr[b], lcnt[b]);
        lcnt[b]  = 0;  // reuse as placement counter
    }
    __syncthreads();
#pragma unroll
    for (int k = 0; k < 16; ++k) {
        if (bk[k] >= 0) {
            int i = s0 + tid + k * 256;
            int p = gbase[bk[k]] + atomicAdd(&lcnt[bk[k]], 1);
            if (p < (bk[k] + 1) * CAPB) recs2[p] = make_int2(src[i], dv[k]);
        }
    }
}

// One block per fine bucket: LDS counting sort -> dense csr, rp/dinv, then
// fused mm1 for this bucket's nodes: t1 = fp16(dinv * x W1^T).
__global__ __launch_bounds__(256) void sortfill_mm_kernel(
    const int2* __restrict__ recs2, const int* __restrict__ fctr,
    int* __restrict__ rp, float* __restrict__ dinv, int* __restrict__ csr,
    const float* __restrict__ x, const float* __restrict__ W1,
    __half* __restrict__ t1, int n) {
    __shared__ int hist[128];
    __shared__ int lofs[129];
    __shared__ int stage[CAPB];
    __shared__ int redbuf[256];
    __shared__ float xrow[98 * 64];  // 25KB
    int g   = blockIdx.x;
    int N0  = (int)(((long long)n * g + 511) / 512);
    int N1  = (int)(((long long)n * (g + 1) + 511) / 512);
    int nn  = N1 - N0;  // <= 98
    int tid = threadIdx.x;
    int lane = tid & 63;
    int wave = tid >> 6;

    int partial = 0;
    for (int j = tid; j < g; j += 256) partial += min(fctr[j], CAPB);
    redbuf[tid] = partial;
    if (tid < 128) hist[tid] = 0;
    __syncthreads();
    for (int s = 128; s > 0; s >>= 1) {
        if (tid < s) redbuf[tid] += redbuf[tid + s];
        __syncthreads();
    }
    int base = redbuf[0];
    const int2* my = recs2 + (size_t)g * CAPB;
    int total = min(fctr[g], CAPB);
    for (int i = tid; i < total; i += 256)
        atomicAdd(&hist[my[i].y - N0], 1);
    __syncthreads();
    if (tid == 0) {
        int acc = 0;
        for (int k = 0; k < nn; ++k) { lofs[k] = acc; acc += hist[k]; }
        lofs[nn] = acc;
    }
    __syncthreads();
    if (tid < 128) hist[tid] = 0;  // placement counters
    __syncthreads();
    for (int i = tid; i < total; i += 256) {
        int2 rec = my[i];
        int  li  = rec.y - N0;
        int  pos = lofs[li] + atomicAdd(&hist[li], 1);
        stage[pos] = rec.x;  // pos < total <= CAPB
    }
    __syncthreads();
    for (int j = tid; j < total; j += 256) csr[base + j] = stage[j];
    if (tid < nn) {
        rp[N0 + tid]   = base + lofs[tid];
        int deg        = lofs[tid + 1] - lofs[tid];
        dinv[N0 + tid] = rsqrtf((float)(deg + 1));
    }
    if (g == 511 && tid == 0) rp[n] = base + total;

    // ---- fused mm1 for this bucket's nodes ----
    for (int idx = tid; idx < nn * 16; idx += 256)
        ((float4*)xrow)[idx] = ((const float4*)(x + (size_t)N0 * 64))[idx];
    float4 wreg[16];
    const float4* W4 = (const float4*)(W1 + lane * 64);
#pragma unroll
    for (int q = 0; q < 16; ++q) wreg[q] = W4[q];
    __syncthreads();
    for (int li = wave; li < nn; li += 4) {
        float dv = rsqrtf((float)(lofs[li + 1] - lofs[li] + 1));
        const float4* row = (const float4*)(xrow + li * 64);
        float acc = 0.0f;
#pragma unroll
        for (int q = 0; q < 16; ++q) {
            float4 hv = row[q];  // wave-uniform -> LDS broadcast
            acc += hv.x * wreg[q].x + hv.y * wreg[q].y +
                   hv.z * wreg[q].z + hv.w * wreg[q].w;
        }
        t1[(size_t)(N0 + li) * 64 + lane] = __float2half(acc * dv);
    }
}

// Fused agg(layer k) + mm(layer k+1): 512 thr = 8 waves, 32 nodes/block.
// GATHER: one node per 16-lane group; lane owns features 4c..4c+3 EXCLUSIVELY
// (no cross-lane reduce). 8-deep index-clamped mask-FMA gather per round ->
// 4 independent nodes/wave = 32 loads in flight. h row -> LDS (fp32).
// MM: proven mm_kernel body: W row per lane in 16 float4 regs, 4 rows/wave
// (W amortized), LDS broadcast h, dense fp16 row store.
__global__ __launch_bounds__(512, 4) void aggmm_kernel(const __half* __restrict__ t,
                                                       const int* __restrict__ rp,
                                                       const int* __restrict__ cs,
                                                       const float* __restrict__ dinv,
                                                       const float* __restrict__ bias,
                                                       const float* __restrict__ W,
                                                       __half* __restrict__ tout, int n) {
    __shared__ float hs[32 * 64];  // 8KB
    __shared__ float dvs[32];
    int tid  = threadIdx.x;
    int lane = tid & 63;
    int wave = tid >> 6;        // 0..7
    int g    = lane >> 4;       // group = node slot 0..3
    int fo   = (lane & 15) << 2;// half offset: lane owns features fo..fo+3
    int base = blockIdx.x * 32;
    int nl   = wave * 4 + g;    // local node 0..31
    int i    = base + nl;

    float4 a0 = make_float4(0.f, 0.f, 0.f, 0.f);
    float4 a1 = a0;
    float2 s01 = make_float2(0.f, 0.f), s23 = s01;
    float  dv = 1.0f;

    if (i < n) {
        int beg = rp[i];
        int end = rp[i + 1];
        uint2 su = *(const uint2*)(t + (size_t)i * 64 + fo);  // self row (early)
        dv = dinv[i];
        for (int eb = beg; eb < end; eb += 8) {
#pragma unroll
            for (int j = 0; j < 8; ++j) {
                int   ej = eb + j;
                int   ec = min(ej, end - 1);         // in-bounds (loop => end>beg)
                int   sj = cs[ec];                   // unconditional load
                uint2 u  = *(const uint2*)(t + (size_t)sj * 64 + fo);
                float m  = (ej < end) ? 1.0f : 0.0f;
                float2 f0 = __half22float2(*(const __half2*)&u.x);
                float2 f1 = __half22float2(*(const __half2*)&u.y);
                if (j & 1) {
                    a1.x = fmaf(m, f0.x, a1.x);
                    a1.y = fmaf(m, f0.y, a1.y);
                    a1.z = fmaf(m, f1.x, a1.z);
                    a1.w = fmaf(m, f1.y, a1.w);
                } else {
                    a0.x = fmaf(m, f0.x, a0.x);
                    a0.y = fmaf(m, f0.y, a0.y);
                    a0.z = fmaf(m, f1.x, a0.z);
                    a0.w = fmaf(m, f1.y, a0.w);
                }
            }
        }
        s01 = __half22float2(*(const __half2*)&su.x);
        s23 = __half22float2(*(const __half2*)&su.y);
    }
    if (i < n) {
        float4 bv = *(const float4*)(bias + fo);
        float4 h4;
        h4.x = fmaxf(fmaf(dv, (a0.x + a1.x) + s01.x, bv.x), 0.0f);
        h4.y = fmaxf(fmaf(dv, (a0.y + a1.y) + s01.y, bv.y), 0.0f);
        h4.z = fmaxf(fmaf(dv, (a0.z + a1.z) + s23.x, bv.z), 0.0f);
        h4.w = fmaxf(fmaf(dv, (a0.w + a1.w) + s23.y, bv.w), 0.0f);
        *(float4*)(hs + nl * 64 + fo) = h4;
        if ((lane & 15) == 0) dvs[nl] = dv;
    }
    __syncthreads();

    // ---- mm phase (mm_kernel body, 4 rows/wave) ----
    float4 wreg[16];
    const float4* W4 = (const float4*)(W + lane * 64);
#pragma unroll
    for (int q = 0; q < 16; ++q) wreg[q] = W4[q];
#pragma unroll
    for (int rr = 0; rr < 4; ++rr) {
        int r  = wave * 4 + rr;
        int io = base + r;
        if (io < n) {
            const float4* row = (const float4*)(hs + r * 64);
            float acc = 0.0f;
#pragma unroll
            for (int q = 0; q < 16; ++q) {
                float4 hv = row[q];  // wave-uniform address -> LDS broadcast
                acc += hv.x * wreg[q].x + hv.y * wreg[q].y +
                       hv.z * wreg[q].z + hv.w * wreg[q].w;
            }
            tout[(size_t)io * 64 + lane] = __float2half(acc * dvs[r]);
        }
    }
}

// Final layer: R21-proven 1-node/wave slice gather -> h3 on all lanes ->
// per-node z = h3 . Wl^T (chunk-aligned Wl frags), xor-reduce over chunks,
// 16 atomicAdds of z*inv_cnt into out (pre-seeded with bl).
__global__ __launch_bounds__(256, 6) void aggfinal_kernel(const __half* __restrict__ t,
                                                          const int* __restrict__ rp,
                                                          const int* __restrict__ cs,
                                                          const float* __restrict__ dinv,
                                                          const float* __restrict__ bias,
                                                          const float* __restrict__ Wl,
                                                          const int* __restrict__ batch,
                                                          const float* __restrict__ invc,
                                                          float* __restrict__ out, int n) {
    int gw   = (blockIdx.x * blockDim.x + threadIdx.x) >> 6;
    int lane = threadIdx.x & 63;
    if (gw >= n) return;
    int i   = gw;
    int grp = lane >> 4;
    int fo  = (lane & 15) << 2;
    int beg = rp[i];
    int end = rp[i + 1];
    uint2 su = *(const uint2*)(t + (size_t)i * 64 + fo);
    float dv = dinv[i];
    float4 bv = *(const float4*)(bias + fo);

    int deg = end - beg;
    int len = (deg + 3) >> 2;
    int gb  = beg + grp * len;
    int ge  = min(gb + len, end);

    float4 aa[4];
    aa[0] = make_float4(0.f, 0.f, 0.f, 0.f);
    aa[1] = aa[0]; aa[2] = aa[0]; aa[3] = aa[0];
    for (int eb = gb; eb < ge; eb += 8) {
#pragma unroll
        for (int j = 0; j < 8; ++j) {
            int   ej = eb + j;
            int   ec = min(ej, end - 1);
            int   sj = cs[ec];
            uint2 u  = *(const uint2*)(t + (size_t)sj * 64 + fo);
            float m  = (ej < ge) ? 1.0f : 0.0f;
            float2 f0 = __half22float2(*(const __half2*)&u.x);
            float2 f1 = __half22float2(*(const __half2*)&u.y);
            aa[j & 3].x = fmaf(m, f0.x, aa[j & 3].x);
            aa[j & 3].y = fmaf(m, f0.y, aa[j & 3].y);
            aa[j & 3].z = fmaf(m, f1.x, aa[j & 3].z);
            aa[j & 3].w = fmaf(m, f1.y, aa[j & 3].w);
        }
    }
    float4 acc;
    acc.x = (aa[0].x + aa[1].x) + (aa[2].x + aa[3].x);
    acc.y = (aa[0].y + aa[1].y) + (aa[2].y + aa[3].y);
    acc.z = (aa[0].z + aa[1].z) + (aa[2].z + aa[3].z);
    acc.w = (aa[0].w + aa[1].w) + (aa[2].w + aa[3].w);
    acc.x += __shfl_xor(acc.x, 16, 64);
    acc.y += __shfl_xor(acc.y, 16, 64);
    acc.z += __shfl_xor(acc.z, 16, 64);
    acc.w += __shfl_xor(acc.w, 16, 64);
    acc.x += __shfl_xor(acc.x, 32, 64);
    acc.y += __shfl_xor(acc.y, 32, 64);
    acc.z += __shfl_xor(acc.z, 32, 64);
    acc.w += __shfl_xor(acc.w, 32, 64);

    // all lanes hold h3[i][4*(lane&15) .. +3]
    float2 s01 = __half22float2(*(const __half2*)&su.x);
    float2 s23 = __half22float2(*(const __half2*)&su.y);
    float4 h4;
    h4.x = fmaxf(fmaf(dv, acc.x + s01.x, bv.x), 0.0f);
    h4.y = fmaxf(fmaf(dv, acc.y + s01.y, bv.y), 0.0f);
    h4.z = fmaxf(fmaf(dv, acc.z + s23.x, bv.z), 0.0f);
    h4.w = fmaxf(fmaf(dv, acc.w + s23.y, bv.w), 0.0f);

    // z[o] = h3 . Wl[o], o = 4m + grp; lane uses only its own chunk.
    float4 wl0 = *(const float4*)(Wl + (0 * 4 + grp) * 64 + fo);
    float4 wl1 = *(const float4*)(Wl + (1 * 4 + grp) * 64 + fo);
    float4 wl2 = *(const float4*)(Wl + (2 * 4 + grp) * 64 + fo);
    float4 wl3 = *(const float4*)(Wl + (3 * 4 + grp) * 64 + fo);
    float z0 = h4.x * wl0.x + h4.y * wl0.y + h4.z * wl0.z + h4.w * wl0.w;
    float z1 = h4.x * wl1.x + h4.y * wl1.y + h4.z * wl1.z + h4.w * wl1.w;
    float z2 = h4.x * wl2.x + h4.y * wl2.y + h4.z * wl2.z + h4.w * wl2.w;
    float z3 = h4.x * wl3.x + h4.y * wl3.y + h4.z * wl3.z + h4.w * wl3.w;
#pragma unroll
    for (int s = 1; s <= 8; s <<= 1) {
        z0 += __shfl_xor(z0, s, 64);
        z1 += __shfl_xor(z1, s, 64);
        z2 += __shfl_xor(z2, s, 64);
        z3 += __shfl_xor(z3, s, 64);
    }
    int m = lane & 15;
    if (m < 4) {
        int   b  = batch[i];
        float ic = invc[b];
        float zv = (m == 0) ? z0 : (m == 1) ? z1 : (m == 2) ? z2 : z3;
        atomicAdd(out + b * 16 + (m * 4 + grp), zv * ic);
    }
}

extern "C" void kernel_launch(void* const* d_in, const int* in_sizes, int n_in,
                              void* d_out, int out_size, void* d_ws, size_t ws_size,
                              hipStream_t stream) {
    const float* x    = (const float*)d_in[0];
    const int*   ei   = (const int*)d_in[1];
    const int*   batch= (const int*)d_in[2];
    const float* W1   = (const float*)d_in[3];
    const float* b1   = (const float*)d_in[4];
    const float* W2   = (const float*)d_in[5];
    const float* b2   = (const float*)d_in[6];
    const float* W3   = (const float*)d_in[7];
    const float* b3   = (const float*)d_in[8];
    const float* Wl   = (const float*)d_in[9];
    const float* bl   = (const float*)d_in[10];
    float* out = (float*)d_out;

    int n  = in_sizes[0] / 64;   // 50000 nodes
    int e  = in_sizes[1] / 2;    // 1250000 edges
    int nb = out_size / 16;      // 512 graphs

    const int* esrc = ei;
    const int* edst = ei + e;

    char* p = (char*)d_ws;
    auto carve = [&](size_t bytes) {
        char* r = p;
        p += (bytes + 255) & ~(size_t)255;
        return r;
    };
    float*  dinv  = (float*)carve((size_t)n * 4);
    int*    rp    = (int*)  carve((size_t)(n + 1) * 4);
    int*    csr   = (int*)  carve((size_t)e * 4);
    __half* tA    = (__half*)carve((size_t)n * 64 * 2);  // t1 / t3
    __half* tB    = (__half*)carve((size_t)n * 64 * 2);  // t2
    int2*   recs2 = (int2*) carve((size_t)512 * CAPB * 8);
    int*    fctr  = (int*)  carve(512 * 4);
    float*  invc  = (float*)carve((size_t)nb * 4);

    dim3 blk(256);
    int gBIN = (e + BINTILE - 1) / BINTILE;  // 306 tiles
    int gFUS = (n + 31) / 32;                // 32 nodes / 512-thr block
    int gAGG = (n + 3) / 4;                  // one node per wave (aggfinal)

    init_kernel<<<2, blk, 0, stream>>>(fctr, batch, bl, invc, out, n, nb);
    bin512_kernel<<<gBIN, blk, 0, stream>>>(esrc, edst, fctr, recs2, e, n);
    sortfill_mm_kernel<<<512, blk, 0, stream>>>(recs2, fctr, rp, dinv, csr,
                                                x, W1, tA, n);
    aggmm_kernel<<<gFUS, dim3(512), 0, stream>>>(tA, rp, csr, dinv, b1, W2, tB, n);
    aggmm_kernel<<<gFUS, dim3(512), 0, stream>>>(tB, rp, csr, dinv, b2, W3, tA, n);
    aggfinal_kernel<<<gAGG, blk, 0, stream>>>(tA, rp, csr, dinv, b3, Wl,
                                              batch, invc, out, n);
}

// Round 4
// 285.983 us; speedup vs baseline: 1.4011x; 1.0042x over previous
//
#include <hip/hip_runtime.h>
#include <hip/hip_fp16.h>

// ---------------------------------------------------------------------------
// GCN (3 layers) + global mean pool + linear, fp32 in/out, MI355X.
// t'[i] = dinv[i] * h[i] W^T; h_next[i] = relu(dinv[i]*(t'[i]+sum t'[j]) + b)
// R3-R5: scattered 4B global stores/atomics = ~32B HBM sector each. Dense only.
// R9: fp16 t (128B row = 1 L2 line), absmax 1.2e-4.
// R13/R18/R20: agg+mm fusion fails if it (a) cuts gather MLP or (b) leaves W
//   unamortized per wave (R20: VGPR=28, serial W reloads, 113us).
// R21: 8-wide masked-parallel gather; aggfinal fuses agg3+pool+linear.
// R22: aggmm fusion (512thr/32 nodes, node per 16-lane group, lane owns 4
//   features, mm via LDS h + W-row regs). 58.7us: NEUTRAL vs split. Counters:
//   hbm 10.7%, VALU 33%, VGPR 48 -> latency-bound; whole-node-per-group made
//   the gather ~3.2 serial rounds x 2 hops (cs->t) = ~8 latency exposures.
// R23 (this round): shfl-broadcast cs preload. Group's 16 lanes load 48 edge
//   indices in 3 INDEPENDENT coalesced loads; index j broadcast via
//   __shfl(c, g*16+j) (register, no mem dep) -> all 48 t-gathers independent
//   -> gather = 2 latency hops total. Tail loop (deg>48, ~1e-5) has
//   group-uniform bounds => shfl sources always active; sj clamped for the
//   deg=0 / cs[e] corner. aggfinal already 2-hop -> unchanged (clean A/B).
// ---------------------------------------------------------------------------

#define CAPB 3072
#define BINTILE 4096

// fctr zero + per-graph inverse counts (binary search on sorted batch) +
// out seeded with bl (aggfinal accumulates atomically on top).
__global__ __launch_bounds__(256) void init_kernel(int* __restrict__ fctr,
                                                   const int* __restrict__ batch,
                                                   const float* __restrict__ bl,
                                                   float* __restrict__ invc,
                                                   float* __restrict__ out,
                                                   int n, int nb) {
    int t = blockIdx.x * blockDim.x + threadIdx.x;
    if (t < 512) fctr[t] = 0;
    if (t < nb) {
        int l = 0, r = n;
        while (l < r) { int m = (l + r) >> 1; if (batch[m] < t) l = m + 1; else r = m; }
        int lo = l;
        r = n;
        while (l < r) { int m = (l + r) >> 1; if (batch[m] < t + 1) l = m + 1; else r = m; }
        invc[t] = 1.0f / fmaxf((float)(l - lo), 1.0f);
#pragma unroll
        for (int o = 0; o < 16; ++o) out[t * 16 + o] = bl[o];
    }
}

// Bucket edges into 512 fine dst-ranges (fixed capacity CAPB, base=g*CAPB).
__global__ __launch_bounds__(256) void bin512_kernel(const int* __restrict__ src,
                                                     const int* __restrict__ dst,
                                                     int* __restrict__ fctr,
                                                     int2* __restrict__ recs2,
                                                     int e, int n) {
    __shared__ int lcnt[512], gbase[512];
    int tid = threadIdx.x;
    int s0  = blockIdx.x * BINTILE;
    lcnt[tid] = 0;
    lcnt[tid + 256] = 0;
    __syncthreads();
    int dv[16], bk[16];
#pragma unroll
    for (int k = 0; k < 16; ++k) {
        int i = s0 + tid + k * 256;  // coalesced
        if (i < e) {
            dv[k] = dst[i];
            bk[k] = (int)((512LL * dv[k]) / n);
            atomicAdd(&lcnt[bk[k]], 1);
        } else {
            bk[k] = -1;
        }
    }
    __syncthreads();
#pragma unroll
    for (int j = 0; j < 2; ++j) {
        int b = tid + j * 256;
        gbase[b] = b * CAPB + atomicAdd(&fctr[b], lcnt[b]);
        lcnt[b]  = 0;  // reuse as placement counter
    }
    __syncthreads();
#pragma unroll
    for (int k = 0; k < 16; ++k) {
        if (bk[k] >= 0) {
            int i = s0 + tid + k * 256;
            int p = gbase[bk[k]] + atomicAdd(&lcnt[bk[k]], 1);
            if (p < (bk[k] + 1) * CAPB) recs2[p] = make_int2(src[i], dv[k]);
        }
    }
}

// One block per fine bucket: LDS counting sort -> dense csr, rp/dinv, then
// fused mm1 for this bucket's nodes: t1 = fp16(dinv * x W1^T).
__global__ __launch_bounds__(256) void sortfill_mm_kernel(
    const int2* __restrict__ recs2, const int* __restrict__ fctr,
    int* __restrict__ rp, float* __restrict__ dinv, int* __restrict__ csr,
    const float* __restrict__ x, const float* __restrict__ W1,
    __half* __restrict__ t1, int n) {
    __shared__ int hist[128];
    __shared__ int lofs[129];
    __shared__ int stage[CAPB];
    __shared__ int redbuf[256];
    __shared__ float xrow[98 * 64];  // 25KB
    int g   = blockIdx.x;
    int N0  = (int)(((long long)n * g + 511) / 512);
    int N1  = (int)(((long long)n * (g + 1) + 511) / 512);
    int nn  = N1 - N0;  // <= 98
    int tid = threadIdx.x;
    int lane = tid & 63;
    int wave = tid >> 6;

    int partial = 0;
    for (int j = tid; j < g; j += 256) partial += min(fctr[j], CAPB);
    redbuf[tid] = partial;
    if (tid < 128) hist[tid] = 0;
    __syncthreads();
    for (int s = 128; s > 0; s >>= 1) {
        if (tid < s) redbuf[tid] += redbuf[tid + s];
        __syncthreads();
    }
    int base = redbuf[0];
    const int2* my = recs2 + (size_t)g * CAPB;
    int total = min(fctr[g], CAPB);
    for (int i = tid; i < total; i += 256)
        atomicAdd(&hist[my[i].y - N0], 1);
    __syncthreads();
    if (tid == 0) {
        int acc = 0;
        for (int k = 0; k < nn; ++k) { lofs[k] = acc; acc += hist[k]; }
        lofs[nn] = acc;
    }
    __syncthreads();
    if (tid < 128) hist[tid] = 0;  // placement counters
    __syncthreads();
    for (int i = tid; i < total; i += 256) {
        int2 rec = my[i];
        int  li  = rec.y - N0;
        int  pos = lofs[li] + atomicAdd(&hist[li], 1);
        stage[pos] = rec.x;  // pos < total <= CAPB
    }
    __syncthreads();
    for (int j = tid; j < total; j += 256) csr[base + j] = stage[j];
    if (tid < nn) {
        rp[N0 + tid]   = base + lofs[tid];
        int deg        = lofs[tid + 1] - lofs[tid];
        dinv[N0 + tid] = rsqrtf((float)(deg + 1));
    }
    if (g == 511 && tid == 0) rp[n] = base + total;

    // ---- fused mm1 for this bucket's nodes ----
    for (int idx = tid; idx < nn * 16; idx += 256)
        ((float4*)xrow)[idx] = ((const float4*)(x + (size_t)N0 * 64))[idx];
    float4 wreg[16];
    const float4* W4 = (const float4*)(W1 + lane * 64);
#pragma unroll
    for (int q = 0; q < 16; ++q) wreg[q] = W4[q];
    __syncthreads();
    for (int li = wave; li < nn; li += 4) {
        float dv = rsqrtf((float)(lofs[li + 1] - lofs[li] + 1));
        const float4* row = (const float4*)(xrow + li * 64);
        float acc = 0.0f;
#pragma unroll
        for (int q = 0; q < 16; ++q) {
            float4 hv = row[q];  // wave-uniform -> LDS broadcast
            acc += hv.x * wreg[q].x + hv.y * wreg[q].y +
                   hv.z * wreg[q].z + hv.w * wreg[q].w;
        }
        t1[(size_t)(N0 + li) * 64 + lane] = __float2half(acc * dv);
    }
}

// Fused agg(layer k) + mm(layer k+1): 512 thr = 8 waves, 32 nodes/block.
// GATHER (R23): group's 16 lanes preload cs[beg..beg+47] in 3 independent
// coalesced loads; edge j's index reaches all group lanes via __shfl
// (register broadcast, no mem dep) -> 48 independent t-gathers = 2 latency
// hops. Mask-FMA, clamped indices (loads unconditional). Tail (deg>48) has
// group-uniform bounds -> shfl sources always exec-active.
// MM: proven mm_kernel body (W row/lane in 16 float4 regs, 4 rows/wave).
__global__ __launch_bounds__(512, 4) void aggmm_kernel(const __half* __restrict__ t,
                                                       const int* __restrict__ rp,
                                                       const int* __restrict__ cs,
                                                       const float* __restrict__ dinv,
                                                       const float* __restrict__ bias,
                                                       const float* __restrict__ W,
                                                       __half* __restrict__ tout, int n) {
    __shared__ float hs[32 * 64];  // 8KB
    __shared__ float dvs[32];
    int tid  = threadIdx.x;
    int lane = tid & 63;
    int wave = tid >> 6;        // 0..7
    int g    = lane >> 4;       // group = node slot 0..3
    int lb   = lane & 15;
    int fo   = lb << 2;         // lane owns features fo..fo+3
    int gs   = g << 4;
    int base = blockIdx.x * 32;
    int nl   = wave * 4 + g;    // local node 0..31
    int i    = base + nl;
    int ii   = min(i, n - 1);   // clamped for tail block; store guarded by i<n

    int beg  = rp[ii];
    int end  = rp[ii + 1];
    int deg  = end - beg;
    int last = max(end - 1, beg);  // deg==0 corner: stays in csr buffer

    // independent early loads: self row, norm, 48 edge indices
    uint2 su = *(const uint2*)(t + (size_t)ii * 64 + fo);
    float dv = dinv[ii];
    int c0 = cs[min(beg + lb,      last)];
    int c1 = cs[min(beg + 16 + lb, last)];
    int c2 = cs[min(beg + 32 + lb, last)];

    float4 a0 = make_float4(0.f, 0.f, 0.f, 0.f);
    float4 a1 = a0, a2 = a0, a3 = a0;

#pragma unroll
    for (int j = 0; j < 16; ++j) {
        int sj = __shfl(c0, gs + j, 64);       // = cs[beg_g + j]
        sj = min(max(sj, 0), n - 1);
        uint2 u  = *(const uint2*)(t + (size_t)sj * 64 + fo);
        float m  = (j < deg) ? 1.0f : 0.0f;
        float2 f0 = __half22float2(*(const __half2*)&u.x);
        float2 f1 = __half22float2(*(const __half2*)&u.y);
        float4& a = (j & 2) ? ((j & 1) ? a3 : a2) : ((j & 1) ? a1 : a0);
        a.x = fmaf(m, f0.x, a.x);
        a.y = fmaf(m, f0.y, a.y);
        a.z = fmaf(m, f1.x, a.z);
        a.w = fmaf(m, f1.y, a.w);
    }
#pragma unroll
    for (int j = 0; j < 16; ++j) {
        int sj = __shfl(c1, gs + j, 64);       // = cs[beg_g + 16 + j]
        sj = min(max(sj, 0), n - 1);
        uint2 u  = *(const uint2*)(t + (size_t)sj * 64 + fo);
        float m  = (16 + j < deg) ? 1.0f : 0.0f;
        float2 f0 = __half22float2(*(const __half2*)&u.x);
        float2 f1 = __half22float2(*(const __half2*)&u.y);
        float4& a = (j & 2) ? ((j & 1) ? a3 : a2) : ((j & 1) ? a1 : a0);
        a.x = fmaf(m, f0.x, a.x);
        a.y = fmaf(m, f0.y, a.y);
        a.z = fmaf(m, f1.x, a.z);
        a.w = fmaf(m, f1.y, a.w);
    }
#pragma unroll
    for (int j = 0; j < 16; ++j) {
        int sj = __shfl(c2, gs + j, 64);       // = cs[beg_g + 32 + j]
        sj = min(max(sj, 0), n - 1);
        uint2 u  = *(const uint2*)(t + (size_t)sj * 64 + fo);
        float m  = (32 + j < deg) ? 1.0f : 0.0f;
        float2 f0 = __half22float2(*(const __half2*)&u.x);
        float2 f1 = __half22float2(*(const __half2*)&u.y);
        float4& a = (j & 2) ? ((j & 1) ? a3 : a2) : ((j & 1) ? a1 : a0);
        a.x = fmaf(m, f0.x, a.x);
        a.y = fmaf(m, f0.y, a.y);
        a.z = fmaf(m, f1.x, a.z);
        a.w = fmaf(m, f1.y, a.w);
    }
    // rare tail (deg > 48, ~1e-5 of nodes); bounds uniform within a group
    for (int b0 = beg + 48; b0 < end; b0 += 16) {
        int rc = cs[min(b0 + lb, end - 1)];
#pragma unroll
        for (int j = 0; j < 16; ++j) {
            int sj = __shfl(rc, gs + j, 64);
            sj = min(max(sj, 0), n - 1);
            uint2 u  = *(const uint2*)(t + (size_t)sj * 64 + fo);
            float m  = (b0 + j < end) ? 1.0f : 0.0f;
            float2 f0 = __half22float2(*(const __half2*)&u.x);
            float2 f1 = __half22float2(*(const __half2*)&u.y);
            float4& a = (j & 2) ? ((j & 1) ? a3 : a2) : ((j & 1) ? a1 : a0);
            a.x = fmaf(m, f0.x, a.x);
            a.y = fmaf(m, f0.y, a.y);
            a.z = fmaf(m, f1.x, a.z);
            a.w = fmaf(m, f1.y, a.w);
        }
    }

    if (i < n) {
        float2 s01 = __half22float2(*(const __half2*)&su.x);
        float2 s23 = __half22float2(*(const __half2*)&su.y);
        float4 bv = *(const float4*)(bias + fo);
        float4 h4;
        h4.x = fmaxf(fmaf(dv, ((a0.x + a1.x) + (a2.x + a3.x)) + s01.x, bv.x), 0.0f);
        h4.y = fmaxf(fmaf(dv, ((a0.y + a1.y) + (a2.y + a3.y)) + s01.y, bv.y), 0.0f);
        h4.z = fmaxf(fmaf(dv, ((a0.z + a1.z) + (a2.z + a3.z)) + s23.x, bv.z), 0.0f);
        h4.w = fmaxf(fmaf(dv, ((a0.w + a1.w) + (a2.w + a3.w)) + s23.y, bv.w), 0.0f);
        *(float4*)(hs + nl * 64 + fo) = h4;
        if (lb == 0) dvs[nl] = dv;
    }
    __syncthreads();

    // ---- mm phase (mm_kernel body, 4 rows/wave) ----
    float4 wreg[16];
    const float4* W4 = (const float4*)(W + lane * 64);
#pragma unroll
    for (int q = 0; q < 16; ++q) wreg[q] = W4[q];
#pragma unroll
    for (int rr = 0; rr < 4; ++rr) {
        int r  = wave * 4 + rr;
        int io = base + r;
        if (io < n) {
            const float4* row = (const float4*)(hs + r * 64);
            float acc = 0.0f;
#pragma unroll
            for (int q = 0; q < 16; ++q) {
                float4 hv = row[q];  // wave-uniform address -> LDS broadcast
                acc += hv.x * wreg[q].x + hv.y * wreg[q].y +
                       hv.z * wreg[q].z + hv.w * wreg[q].w;
            }
            tout[(size_t)io * 64 + lane] = __float2half(acc * dvs[r]);
        }
    }
}

// Final layer: R21-proven 1-node/wave slice gather -> h3 on all lanes ->
// per-node z = h3 . Wl^T (chunk-aligned Wl frags), xor-reduce over chunks,
// 16 atomicAdds of z*inv_cnt into out (pre-seeded with bl).
__global__ __launch_bounds__(256, 6) void aggfinal_kernel(const __half* __restrict__ t,
                                                          const int* __restrict__ rp,
                                                          const int* __restrict__ cs,
                                                          const float* __restrict__ dinv,
                                                          const float* __restrict__ bias,
                                                          const float* __restrict__ Wl,
                                                          const int* __restrict__ batch,
                                                          const float* __restrict__ invc,
                                                          float* __restrict__ out, int n) {
    int gw   = (blockIdx.x * blockDim.x + threadIdx.x) >> 6;
    int lane = threadIdx.x & 63;
    if (gw >= n) return;
    int i   = gw;
    int grp = lane >> 4;
    int fo  = (lane & 15) << 2;
    int beg = rp[i];
    int end = rp[i + 1];
    uint2 su = *(const uint2*)(t + (size_t)i * 64 + fo);
    float dv = dinv[i];
    float4 bv = *(const float4*)(bias + fo);

    int deg = end - beg;
    int len = (deg + 3) >> 2;
    int gb  = beg + grp * len;
    int ge  = min(gb + len, end);

    float4 aa[4];
    aa[0] = make_float4(0.f, 0.f, 0.f, 0.f);
    aa[1] = aa[0]; aa[2] = aa[0]; aa[3] = aa[0];
    for (int eb = gb; eb < ge; eb += 8) {
#pragma unroll
        for (int j = 0; j < 8; ++j) {
            int   ej = eb + j;
            int   ec = min(ej, end - 1);
            int   sj = cs[ec];
            uint2 u  = *(const uint2*)(t + (size_t)sj * 64 + fo);
            float m  = (ej < ge) ? 1.0f : 0.0f;
            float2 f0 = __half22float2(*(const __half2*)&u.x);
            float2 f1 = __half22float2(*(const __half2*)&u.y);
            aa[j & 3].x = fmaf(m, f0.x, aa[j & 3].x);
            aa[j & 3].y = fmaf(m, f0.y, aa[j & 3].y);
            aa[j & 3].z = fmaf(m, f1.x, aa[j & 3].z);
            aa[j & 3].w = fmaf(m, f1.y, aa[j & 3].w);
        }
    }
    float4 acc;
    acc.x = (aa[0].x + aa[1].x) + (aa[2].x + aa[3].x);
    acc.y = (aa[0].y + aa[1].y) + (aa[2].y + aa[3].y);
    acc.z = (aa[0].z + aa[1].z) + (aa[2].z + aa[3].z);
    acc.w = (aa[0].w + aa[1].w) + (aa[2].w + aa[3].w);
    acc.x += __shfl_xor(acc.x, 16, 64);
    acc.y += __shfl_xor(acc.y, 16, 64);
    acc.z += __shfl_xor(acc.z, 16, 64);
    acc.w += __shfl_xor(acc.w, 16, 64);
    acc.x += __shfl_xor(acc.x, 32, 64);
    acc.y += __shfl_xor(acc.y, 32, 64);
    acc.z += __shfl_xor(acc.z, 32, 64);
    acc.w += __shfl_xor(acc.w, 32, 64);

    // all lanes hold h3[i][4*(lane&15) .. +3]
    float2 s01 = __half22float2(*(const __half2*)&su.x);
    float2 s23 = __half22float2(*(const __half2*)&su.y);
    float4 h4;
    h4.x = fmaxf(fmaf(dv, acc.x + s01.x, bv.x), 0.0f);
    h4.y = fmaxf(fmaf(dv, acc.y + s01.y, bv.y), 0.0f);
    h4.z = fmaxf(fmaf(dv, acc.z + s23.x, bv.z), 0.0f);
    h4.w = fmaxf(fmaf(dv, acc.w + s23.y, bv.w), 0.0f);

    // z[o] = h3 . Wl[o], o = 4m + grp; lane uses only its own chunk.
    float4 wl0 = *(const float4*)(Wl + (0 * 4 + grp) * 64 + fo);
    float4 wl1 = *(const float4*)(Wl + (1 * 4 + grp) * 64 + fo);
    float4 wl2 = *(const float4*)(Wl + (2 * 4 + grp) * 64 + fo);
    float4 wl3 = *(const float4*)(Wl + (3 * 4 + grp) * 64 + fo);
    float z0 = h4.x * wl0.x + h4.y * wl0.y + h4.z * wl0.z + h4.w * wl0.w;
    float z1 = h4.x * wl1.x + h4.y * wl1.y + h4.z * wl1.z + h4.w * wl1.w;
    float z2 = h4.x * wl2.x + h4.y * wl2.y + h4.z * wl2.z + h4.w * wl2.w;
    float z3 = h4.x * wl3.x + h4.y * wl3.y + h4.z * wl3.z + h4.w * wl3.w;
#pragma unroll
    for (int s = 1; s <= 8; s <<= 1) {
        z0 += __shfl_xor(z0, s, 64);
        z1 += __shfl_xor(z1, s, 64);
        z2 += __shfl_xor(z2, s, 64);
        z3 += __shfl_xor(z3, s, 64);
    }
    int m = lane & 15;
    if (m < 4) {
        int   b  = batch[i];
        float ic = invc[b];
        float zv = (m == 0) ? z0 : (m == 1) ? z1 : (m == 2) ? z2 : z3;
        atomicAdd(out + b * 16 + (m * 4 + grp), zv * ic);
    }
}

extern "C" void kernel_launch(void* const* d_in, const int* in_sizes, int n_in,
                              void* d_out, int out_size, void* d_ws, size_t ws_size,
                              hipStream_t stream) {
    const float* x    = (const float*)d_in[0];
    const int*   ei   = (const int*)d_in[1];
    const int*   batch= (const int*)d_in[2];
    const float* W1   = (const float*)d_in[3];
    const float* b1   = (const float*)d_in[4];
    const float* W2   = (const float*)d_in[5];
    const float* b2   = (const float*)d_in[6];
    const float* W3   = (const float*)d_in[7];
    const float* b3   = (const float*)d_in[8];
    const float* Wl   = (const float*)d_in[9];
    const float* bl   = (const float*)d_in[10];
    float* out = (float*)d_out;

    int n  = in_sizes[0] / 64;   // 50000 nodes
    int e  = in_sizes[1] / 2;    // 1250000 edges
    int nb = out_size / 16;      // 512 graphs

    const int* esrc = ei;
    const int* edst = ei + e;

    char* p = (char*)d_ws;
    auto carve = [&](size_t bytes) {
        char* r = p;
        p += (bytes + 255) & ~(size_t)255;
        return r;
    };
    float*  dinv  = (float*)carve((size_t)n * 4);
    int*    rp    = (int*)  carve((size_t)(n + 1) * 4);
    int*    csr   = (int*)  carve((size_t)e * 4);
    __half* tA    = (__half*)carve((size_t)n * 64 * 2);  // t1 / t3
    __half* tB    = (__half*)carve((size_t)n * 64 * 2);  // t2
    int2*   recs2 = (int2*) carve((size_t)512 * CAPB * 8);
    int*    fctr  = (int*)  carve(512 * 4);
    float*  invc  = (float*)carve((size_t)nb * 4);

    dim3 blk(256);
    int gBIN = (e + BINTILE - 1) / BINTILE;  // 306 tiles
    int gFUS = (n + 31) / 32;                // 32 nodes / 512-thr block
    int gAGG = (n + 3) / 4;                  // one node per wave (aggfinal)

    init_kernel<<<2, blk, 0, stream>>>(fctr, batch, bl, invc, out, n, nb);
    bin512_kernel<<<gBIN, blk, 0, stream>>>(esrc, edst, fctr, recs2, e, n);
    sortfill_mm_kernel<<<512, blk, 0, stream>>>(recs2, fctr, rp, dinv, csr,
                                                x, W1, tA, n);
    aggmm_kernel<<<gFUS, dim3(512), 0, stream>>>(tA, rp, csr, dinv, b1, W2, tB, n);
    aggmm_kernel<<<gFUS, dim3(512), 0, stream>>>(tB, rp, csr, dinv, b2, W3, tA, n);
    aggfinal_kernel<<<gAGG, blk, 0, stream>>>(tA, rp, csr, dinv, b3, Wl,
                                              batch, invc, out, n);
}